// Round 7
// baseline (108.417 us; speedup 1.0000x reference)
//
#include <hip/hip_runtime.h>
#include <hip/hip_bf16.h>
#include <math.h>

#define B_    8
#define C_    256
#define L_    4096
#define OCH_  256

typedef __attribute__((ext_vector_type(8)))  short bf16x8;
typedef __attribute__((ext_vector_type(16))) float f32x16;
typedef __attribute__((ext_vector_type(4)))  int   i32x4;

static __device__ __forceinline__ unsigned short bf16_rne(float f) {
    unsigned u = __float_as_uint(f);
    unsigned r = u + 0x7FFFu + ((u >> 16) & 1u);
    return (unsigned short)(r >> 16);
}

static __device__ __forceinline__ void gload_lds16(const void* g, void* l) {
    __builtin_amdgcn_global_load_lds(
        (const __attribute__((address_space(1))) unsigned int*)g,
        (__attribute__((address_space(3))) unsigned int*)l, 16, 0, 0);
}

// ---------------------------------------------------------------------------
// K0: split W[o][c][k] -> k-major bf16 hi/lo: W*[o][k*256+c]
// ---------------------------------------------------------------------------
__global__ void k_split(const float* __restrict__ W,
                        unsigned short* __restrict__ Whi,
                        unsigned short* __restrict__ Wlo) {
    int i = blockIdx.x * 256 + threadIdx.x;          // o*768 + c*3 + k
    if (i >= OCH_ * C_ * 3) return;
    int k = i % 3;
    int c = (i / 3) & 255;
    int o = i / 768;
    float w = W[i];
    unsigned short hb = bf16_rne(w);
    float hi = __uint_as_float((unsigned)hb << 16);
    int dst = o * 768 + k * 256 + c;
    Whi[dst] = hb;
    Wlo[dst] = bf16_rne(w - hi);
}

// ---------------------------------------------------------------------------
// K1: offset network. Wave g = group g; wave 0 finishes softmax and emits
// window-form coef[(b*3+t)*L + l] = { d0, d1, bits(i0f2), 0 }:
//   sampled = x[i0f2]*d0 + x[i0f2+1]*d1  (clamp/validity/mod pre-folded)
// ---------------------------------------------------------------------------
__global__ __launch_bounds__(256) void k_offsets(
        const float* __restrict__ x,
        const float* __restrict__ w1, const float* __restrict__ b1,
        const float* __restrict__ w2, const float* __restrict__ b2,
        float4* __restrict__ coef) {
    __shared__ float sOm[64][37];
    int tid  = threadIdx.x;
    int lane = tid & 63;
    int g    = tid >> 6;
    int blk  = blockIdx.x;
    int b    = blk & 7;                              // XCD affinity
    int l0   = (blk >> 3) << 6;
    int l    = l0 + lane;

    const float* xg = x + (size_t)b * C_ * L_ + (size_t)(g * 64) * L_ + l;

    float h[16];
    #pragma unroll
    for (int o = 0; o < 16; ++o) h[o] = b1[g * 16 + o];
    #pragma unroll 4
    for (int cg = 0; cg < 64; ++cg) {
        float xv = xg[(size_t)cg * L_];
        const float* w1p = w1 + (g * 16) * 64 + cg;
        #pragma unroll
        for (int o = 0; o < 16; ++o) h[o] = fmaf(xv, w1p[o * 64], h[o]);
    }
    float om9[9];
    #pragma unroll
    for (int j = 0; j < 9; ++j) om9[j] = b2[g * 9 + j];
    #pragma unroll
    for (int o = 0; o < 16; ++o) {
        float a  = h[o];
        float hv = 0.5f * a * (1.0f + erff(a * 0.70710678118654752f));
        const float* w2p = w2 + g * 144 + o;         // w2[g][j][o]
        #pragma unroll
        for (int j = 0; j < 9; ++j) om9[j] = fmaf(hv, w2p[j * 16], om9[j]);
    }
    #pragma unroll
    for (int j = 0; j < 9; ++j) sOm[lane][g * 9 + j] = om9[j];
    __syncthreads();
    if (g != 0) return;

    float om[36];
    #pragma unroll
    for (int j = 0; j < 36; ++j) om[j] = sOm[lane][j];
    om[1] = 0.0f; om[3] = 0.0f; om[5] = 0.0f;
    float m = om[3];
    #pragma unroll
    for (int j = 4; j < 36; ++j) m = fmaxf(m, om[j]);
    float ssum = 0.0f;
    #pragma unroll
    for (int j = 3; j < 36; ++j) ssum += expf(om[j] - m);
    float inv = 1.0f / ssum;

    float base = -1.0f + 2.0f * (float)l / (float)(L_ - 1);
    #pragma unroll
    for (int t = 0; t < 3; ++t) {
        float mod  = expf(om[3 + t] - m) * inv;
        float off  = om[2 * t] * (2.0f / (float)L_);
        float grid = base + (-0.5f + 0.5f * (float)t) + off;
        float pp   = (grid + 1.0f) * 0.5f * (float)(L_ - 1);
        float fp   = floorf(pp);
        int i0 = (int)fp, i1 = i0 + 1;
        float w = pp - fp;
        float c0 = (i0 >= 0 && i0 < L_) ? (1.0f - w) * mod : 0.0f;
        float c1 = (i1 >= 0 && i1 < L_) ? w * mod : 0.0f;
        int i0c  = min(max(i0, 0), L_ - 1);
        int i1c  = min(max(i1, 0), L_ - 1);
        int i0f2 = min(max(i0, 0), L_ - 2);
        float d0 = (i0c == i0f2     ? c0 : 0.0f) + (i1c == i0f2     ? c1 : 0.0f);
        float d1 = (i0c == i0f2 + 1 ? c0 : 0.0f) + (i1c == i0f2 + 1 ? c1 : 0.0f);
        coef[((size_t)b * 3 + t) * L_ + l] =
            make_float4(d0, d1, __int_as_float(i0f2), 0.0f);
    }
}

// ---------------------------------------------------------------------------
// K2: materialize sampled matrix S in GEMM-blocked layout:
//   S[b][lt][s][l] : i32x4 = 8 bf16 for kk in [8s, 8s+8), l-tile lt of 64.
// Thread = (b, lt, s, l): 8 near-coalesced gathers -> pack -> 1 dwordx4 store.
// ---------------------------------------------------------------------------
__global__ __launch_bounds__(256) void k_sample(
        const float* __restrict__ x, const float4* __restrict__ coef,
        i32x4* __restrict__ Sg) {
    int tid  = threadIdx.x;
    int l    = tid & 63;
    int unit = tid >> 6;
    int bid  = blockIdx.x;
    int b    = bid & 7;                              // XCD affinity (x[b] hot)
    int r    = bid >> 3;
    int lt   = r & 63;
    int sg   = r >> 6;                               // 0..23
    int s    = sg * 4 + unit;                        // 0..95
    int tap  = s >> 5;
    int c0   = s * 8 - tap * 256;
    int lg   = lt * 64 + l;

    float4 cf = coef[((size_t)b * 3 + tap) * L_ + lg];
    float d0 = cf.x, d1 = cf.y;
    int   i0 = __float_as_int(cf.z);

    const float* xp = x + ((size_t)(b * 256 + c0)) * L_ + i0;
    union { unsigned short us[8]; i32x4 v; } pk;
    #pragma unroll
    for (int e = 0; e < 8; ++e) {
        float g0 = xp[0], g1 = xp[1];
        pk.us[e] = bf16_rne(fmaf(g1, d1, g0 * d0));
        xp += L_;
    }
    Sg[((size_t)(b * 64 + lt) * 96 + s) * 64 + l] = pk.v;
}

// ---------------------------------------------------------------------------
// K3: clean 2-pass split-precision MFMA GEMM.
// Block 512 thr (8 waves) -> 256o x 64l; wave wv owns o-rows wv*32..+32.
// K=768 k-major, chunk 128, dbuf LDS; S staged via linear global_load_lds
// (2 issues/chunk, zero staging VALU/registers). acc = Whi*Shi + Wlo*Shi.
// ---------------------------------------------------------------------------
__global__ __launch_bounds__(512, 4) void k_gemm(
        const unsigned short* __restrict__ Whi,
        const unsigned short* __restrict__ Wlo,
        const float* __restrict__ bias,
        const i32x4* __restrict__ Sg,
        float* __restrict__ out) {
    __shared__ i32x4 sS[2][1024];                    // 32 KB

    const int tid  = threadIdx.x;
    const int lane = tid & 63;
    const int wv   = tid >> 6;                       // 0..7
    const int blk  = blockIdx.x;
    const int b    = blk & 7;                        // XCD affinity
    const int lt   = blk >> 3;
    const int l0   = lt * 64;
    const int q    = lane >> 5;
    const int l31  = lane & 31;

    const i32x4* Sblk = Sg + (size_t)(b * 64 + lt) * (96 * 64);

    const unsigned short* WhP = Whi + (size_t)(wv * 32 + l31) * 768;
    const unsigned short* WlP = Wlo + (size_t)(wv * 32 + l31) * 768;

    f32x16 acc0, acc1;
    #pragma unroll
    for (int i = 0; i < 16; ++i) { acc0[i] = 0.f; acc1[i] = 0.f; }

    // prologue: stage chunk 0 into buf 0 (linear, 2 x 8KB rounds)
    gload_lds16(Sblk + tid,       &sS[0][tid]);
    gload_lds16(Sblk + 512 + tid, &sS[0][512 + tid]);
    __syncthreads();

    #pragma unroll 2
    for (int ch = 0; ch < 6; ++ch) {
        const int buf = ch & 1;
        if (ch < 5) {                                // prefetch next chunk
            const i32x4* src = Sblk + (ch + 1) * 1024;
            gload_lds16(src + tid,       &sS[buf ^ 1][tid]);
            gload_lds16(src + 512 + tid, &sS[buf ^ 1][512 + tid]);
        }
        const int kb = ch * 128 + q * 8;
        bf16x8 aH0 = *(const bf16x8*)(WhP + kb);
        bf16x8 aL0 = *(const bf16x8*)(WlP + kb);
        #pragma unroll
        for (int ks2 = 0; ks2 < 4; ++ks2) {
            bf16x8 aH1 = *(const bf16x8*)(WhP + kb + (ks2 * 2 + 1) * 16);
            bf16x8 aL1 = *(const bf16x8*)(WlP + kb + (ks2 * 2 + 1) * 16);
            {
                const i32x4* bp = &sS[buf][(ks2 * 4 + q) * 64 + l31];
                bf16x8 bh0 = *(const bf16x8*)bp;
                bf16x8 bh1 = *(const bf16x8*)(bp + 32);
                __builtin_amdgcn_s_setprio(1);
                acc0 = __builtin_amdgcn_mfma_f32_32x32x16_bf16(aH0, bh0, acc0, 0, 0, 0);
                acc0 = __builtin_amdgcn_mfma_f32_32x32x16_bf16(aL0, bh0, acc0, 0, 0, 0);
                acc1 = __builtin_amdgcn_mfma_f32_32x32x16_bf16(aH0, bh1, acc1, 0, 0, 0);
                acc1 = __builtin_amdgcn_mfma_f32_32x32x16_bf16(aL0, bh1, acc1, 0, 0, 0);
                __builtin_amdgcn_s_setprio(0);
            }
            if (ks2 < 3) {
                aH0 = *(const bf16x8*)(WhP + kb + (ks2 * 2 + 2) * 16);
                aL0 = *(const bf16x8*)(WlP + kb + (ks2 * 2 + 2) * 16);
            }
            {
                const i32x4* bp = &sS[buf][(ks2 * 4 + 2 + q) * 64 + l31];
                bf16x8 bh0 = *(const bf16x8*)bp;
                bf16x8 bh1 = *(const bf16x8*)(bp + 32);
                __builtin_amdgcn_s_setprio(1);
                acc0 = __builtin_amdgcn_mfma_f32_32x32x16_bf16(aH1, bh0, acc0, 0, 0, 0);
                acc0 = __builtin_amdgcn_mfma_f32_32x32x16_bf16(aL1, bh0, acc0, 0, 0, 0);
                acc1 = __builtin_amdgcn_mfma_f32_32x32x16_bf16(aH1, bh1, acc1, 0, 0, 0);
                acc1 = __builtin_amdgcn_mfma_f32_32x32x16_bf16(aL1, bh1, acc1, 0, 0, 0);
                __builtin_amdgcn_s_setprio(0);
            }
        }
        __syncthreads();                             // drains stage vmcnt too
    }

    // epilogue: bias + store. D: col=lane&31, row=(reg&3)+8*(reg>>2)+4*q
    #pragma unroll
    for (int reg = 0; reg < 16; ++reg) {
        int rr = (reg & 3) + 8 * (reg >> 2) + 4 * q;
        int o  = wv * 32 + rr;
        float bv = bias[o];
        float* op = out + ((size_t)b * 256 + o) * L_ + l0 + l31;
        op[0]  = acc0[reg] + bv;
        op[32] = acc1[reg] + bv;
    }
}

// ---------------------------------------------------------------------------
// Fallback fused kernel (R6) in case ws_size cannot hold S (48 MB).
// ---------------------------------------------------------------------------
__global__ __launch_bounds__(512, 4) void k_conv_fused(
        const float* __restrict__ x,
        const unsigned short* __restrict__ Whi,
        const unsigned short* __restrict__ Wlo,
        const float* __restrict__ bias,
        const float4* __restrict__ coef,
        float* __restrict__ out) {
    __shared__ i32x4 sS[2][16][64];

    const int tid  = threadIdx.x;
    const int lane = tid & 63;
    const int wv   = tid >> 6;
    const int blk  = blockIdx.x;
    const int b    = blk & 7;
    const int l0   = (blk >> 3) * 64;
    const int q    = lane >> 5;
    const int l31  = lane & 31;

    const float* xb = x + (size_t)b * (C_ * L_);

    int iba[3]; float d0a[3], d1a[3];
    #pragma unroll
    for (int t = 0; t < 3; ++t) {
        float4 cf = coef[((size_t)b * 3 + t) * L_ + l0 + lane];
        d0a[t] = cf.x; d1a[t] = cf.y; iba[t] = __float_as_int(cf.z);
    }

    const unsigned short* WhP = Whi + (size_t)(wv * 32 + l31) * 768;
    const unsigned short* WlP = Wlo + (size_t)(wv * 32 + l31) * 768;

    f32x16 acc0, acc1;
    #pragma unroll
    for (int i = 0; i < 16; ++i) { acc0[i] = 0.f; acc1[i] = 0.f; }

    float g0[16], g1[16];
    {
        const float* xc = xb + (size_t)(wv * 16) * L_ + iba[0];
        #pragma unroll
        for (int j = 0; j < 16; ++j) {
            g0[j] = xc[(size_t)j * L_];
            g1[j] = xc[(size_t)j * L_ + 1];
        }
        float d0 = d0a[0], d1 = d1a[0];
        #pragma unroll
        for (int sp = 0; sp < 2; ++sp) {
            union { unsigned short us[8]; i32x4 v; } ph;
            #pragma unroll
            for (int e = 0; e < 8; ++e)
                ph.us[e] = bf16_rne(fmaf(g1[sp * 8 + e], d1, g0[sp * 8 + e] * d0));
            sS[0][wv * 2 + sp][lane] = ph.v;
        }
    }
    __syncthreads();

    #pragma unroll 2
    for (int ch = 0; ch < 6; ++ch) {
        const int buf = ch & 1;
        if (ch < 5) {
            int kk0n = (ch + 1) * 128 + wv * 16;
            int tap  = kk0n >> 8;
            int ib   = tap == 2 ? iba[2] : tap == 1 ? iba[1] : iba[0];
            const float* xc = xb + (size_t)(kk0n & 255) * L_ + ib;
            #pragma unroll
            for (int j = 0; j < 16; ++j) {
                g0[j] = xc[(size_t)j * L_];
                g1[j] = xc[(size_t)j * L_ + 1];
            }
        }
        {
            const int kb = ch * 128 + q * 8;
            bf16x8 aH0 = *(const bf16x8*)(WhP + kb);
            bf16x8 aL0 = *(const bf16x8*)(WlP + kb);
            #pragma unroll
            for (int ks2 = 0; ks2 < 4; ++ks2) {
                bf16x8 aH1 = *(const bf16x8*)(WhP + kb + (ks2 * 2 + 1) * 16);
                bf16x8 aL1 = *(const bf16x8*)(WlP + kb + (ks2 * 2 + 1) * 16);
                {
                    const i32x4* bp = &sS[buf][ks2 * 4 + q][l31];
                    bf16x8 bh0 = *(const bf16x8*)bp;
                    bf16x8 bh1 = *(const bf16x8*)(bp + 32);
                    acc0 = __builtin_amdgcn_mfma_f32_32x32x16_bf16(aH0, bh0, acc0, 0, 0, 0);
                    acc0 = __builtin_amdgcn_mfma_f32_32x32x16_bf16(aL0, bh0, acc0, 0, 0, 0);
                    acc1 = __builtin_amdgcn_mfma_f32_32x32x16_bf16(aH0, bh1, acc1, 0, 0, 0);
                    acc1 = __builtin_amdgcn_mfma_f32_32x32x16_bf16(aL0, bh1, acc1, 0, 0, 0);
                }
                if (ks2 < 3) {
                    aH0 = *(const bf16x8*)(WhP + kb + (ks2 * 2 + 2) * 16);
                    aL0 = *(const bf16x8*)(WlP + kb + (ks2 * 2 + 2) * 16);
                }
                {
                    const i32x4* bp = &sS[buf][ks2 * 4 + 2 + q][l31];
                    bf16x8 bh0 = *(const bf16x8*)bp;
                    bf16x8 bh1 = *(const bf16x8*)(bp + 32);
                    acc0 = __builtin_amdgcn_mfma_f32_32x32x16_bf16(aH1, bh0, acc0, 0, 0, 0);
                    acc0 = __builtin_amdgcn_mfma_f32_32x32x16_bf16(aL1, bh0, acc0, 0, 0, 0);
                    acc1 = __builtin_amdgcn_mfma_f32_32x32x16_bf16(aH1, bh1, acc1, 0, 0, 0);
                    acc1 = __builtin_amdgcn_mfma_f32_32x32x16_bf16(aL1, bh1, acc1, 0, 0, 0);
                }
            }
        }
        if (ch < 5) {
            int kk0n = (ch + 1) * 128 + wv * 16;
            int tap  = kk0n >> 8;
            float d0 = tap == 2 ? d0a[2] : tap == 1 ? d0a[1] : d0a[0];
            float d1 = tap == 2 ? d1a[2] : tap == 1 ? d1a[1] : d1a[0];
            const int nbuf = buf ^ 1;
            #pragma unroll
            for (int sp = 0; sp < 2; ++sp) {
                union { unsigned short us[8]; i32x4 v; } ph;
                #pragma unroll
                for (int e = 0; e < 8; ++e)
                    ph.us[e] = bf16_rne(fmaf(g1[sp * 8 + e], d1, g0[sp * 8 + e] * d0));
                sS[nbuf][wv * 2 + sp][lane] = ph.v;
            }
        }
        __syncthreads();
    }

    #pragma unroll
    for (int reg = 0; reg < 16; ++reg) {
        int rr = (reg & 3) + 8 * (reg >> 2) + 4 * q;
        int o  = wv * 32 + rr;
        float bv = bias[o];
        float* op = out + ((size_t)b * 256 + o) * L_ + l0 + l31;
        op[0]  = acc0[reg] + bv;
        op[32] = acc1[reg] + bv;
    }
}

// ---------------------------------------------------------------------------
extern "C" void kernel_launch(void* const* d_in, const int* in_sizes, int n_in,
                              void* d_out, int out_size, void* d_ws, size_t ws_size,
                              hipStream_t stream) {
    const float* x      = (const float*)d_in[0];
    const float* weight = (const float*)d_in[1];
    const float* bias   = (const float*)d_in[2];
    const float* w1     = (const float*)d_in[3];
    const float* b1     = (const float*)d_in[4];
    const float* w2     = (const float*)d_in[5];
    const float* b2     = (const float*)d_in[6];
    float* out = (float*)d_out;

    const size_t COEF_B = (size_t)B_ * 3 * L_ * sizeof(float4);   // 1.5 MB
    const size_t W_B    = (size_t)OCH_ * C_ * 3 * 2;              // 384 KB
    const size_t S_B    = (size_t)B_ * 64 * 96 * 64 * 16;         // 48 MB
    char* ws = (char*)d_ws;
    float4*         coef = (float4*)ws;
    unsigned short* Whi  = (unsigned short*)(ws + COEF_B);
    unsigned short* Wlo  = (unsigned short*)(ws + COEF_B + W_B);
    i32x4*          Sg   = (i32x4*)(ws + COEF_B + 2 * W_B);

    k_split<<<(OCH_ * C_ * 3 + 255) / 256, 256, 0, stream>>>(weight, Whi, Wlo);
    k_offsets<<<B_ * (L_ / 64), 256, 0, stream>>>(x, w1, b1, w2, b2, coef);

    if (ws_size >= COEF_B + 2 * W_B + S_B) {
        k_sample<<<B_ * 64 * 24, 256, 0, stream>>>(x, coef, Sg);
        k_gemm<<<B_ * (L_ / 64), 512, 0, stream>>>(Whi, Wlo, bias, Sg, out);
    } else {
        k_conv_fused<<<B_ * (L_ / 64), 512, 0, stream>>>(x, Whi, Wlo, bias, coef, out);
    }
}